// Round 10
// baseline (297.396 us; speedup 1.0000x reference)
//
#include <hip/hip_runtime.h>
#include <hip/hip_bf16.h>

#define NN 50000
#define NE 600000
#define DD 128
#define NH 4
#define ET (NE + NN)
#define NEG_SLOPE 0.2f
#define NB 196  // ceil(NN/256) scan blocks

typedef __attribute__((ext_vector_type(8))) short short8;
typedef __attribute__((ext_vector_type(4))) float f32x4;

__device__ __forceinline__ float bf2f(unsigned short u) {
    union { unsigned int i; float f; } c; c.i = ((unsigned int)u) << 16; return c.f;
}
__device__ __forceinline__ unsigned short f2bf(float f) {
    union { float f; unsigned int i; } c; c.f = f;
    unsigned int r = c.i + 0x7FFF + ((c.i >> 16) & 1);  // RNE
    return (unsigned short)(r >> 16);
}
__device__ __forceinline__ float sel4(float4 v, int hc) {
    return (hc & 2) ? ((hc & 1) ? v.w : v.z) : ((hc & 1) ? v.y : v.x);
}

// ---------------- prep: W->bf16, transposed [col][k], chunk-swizzled; counts=0 ----------------
// Layout: Wt[mat*16384 + col*128 + cs*8 + j] = W[k][col], where c = cs^(col&7), k = c*8+j.

__global__ void __launch_bounds__(256) prep_k(const float* __restrict__ W1, const float* __restrict__ Ws1,
                                              const float* __restrict__ W2, const float* __restrict__ Ws2,
                                              unsigned short* __restrict__ Wt, int* __restrict__ counts) {
    int idx = blockIdx.x * 256 + threadIdx.x;  // 0..65535
    int mat = idx >> 14;
    int p = idx & 16383;
    int col = p >> 7;
    int cs = (p >> 3) & 15;
    int j = p & 7;
    int c = cs ^ (col & 7);
    int k = c * 8 + j;
    const float* Wsrc = (mat == 0) ? W1 : (mat == 1) ? Ws1 : (mat == 2) ? W2 : Ws2;
    Wt[idx] = f2bf(Wsrc[k * DD + col]);
    if (idx < NN) counts[idx] = 0;  // real-edge count only; +1 self loop added in scan
}

// ---------------- two-level scan, 2 dispatches (coalesced + monotone) ----------------

__global__ void __launch_bounds__(256) partial_k(const int* __restrict__ counts, int* __restrict__ bsum) {
    __shared__ int tmp[256];
    int t = blockIdx.x * 256 + threadIdx.x;
    int v = (t < NN) ? counts[t] + 1 : 0;  // +1 self loop
    tmp[threadIdx.x] = v;
    __syncthreads();
    for (int off = 128; off > 0; off >>= 1) {
        if (threadIdx.x < off) tmp[threadIdx.x] += tmp[threadIdx.x + off];
        __syncthreads();
    }
    if (threadIdx.x == 0) bsum[blockIdx.x] = tmp[0];
}

// each block recomputes the global prefix of block sums itself (196 ints), then local scan
__global__ void __launch_bounds__(256) offsets_k(const int* __restrict__ counts, const int* __restrict__ bsum,
                                                 int* __restrict__ offsets, int* __restrict__ cursor,
                                                 int* __restrict__ esrc) {
    __shared__ int bs[256];
    __shared__ int tmp[256];
    int b = blockIdx.x, tid = threadIdx.x;
    int bv = (tid < NB) ? bsum[tid] : 0;
    bs[tid] = bv;
    __syncthreads();
    for (int off = 1; off < 256; off <<= 1) {
        int u = (tid >= off) ? bs[tid - off] : 0;
        __syncthreads();
        bs[tid] += u;
        __syncthreads();
    }
    int boff = (b == 0) ? 0 : bs[b - 1];

    int t = b * 256 + tid;
    int c = (t < NN) ? counts[t] : 0;
    int v = (t < NN) ? c + 1 : 0;
    tmp[tid] = v;
    __syncthreads();
    for (int off = 1; off < 256; off <<= 1) {
        int u = (tid >= off) ? tmp[tid - off] : 0;
        __syncthreads();
        tmp[tid] += u;
        __syncthreads();
    }
    if (t < NN) {
        int o = boff + tmp[tid] - v;
        offsets[t] = o;
        cursor[t] = o;
        esrc[o + c] = t;  // self loop in the last slot of the segment
    }
    if (b == 0 && tid == 0) offsets[NN] = ET;
}

__global__ void __launch_bounds__(256) scatter_k(const int* __restrict__ src, const int* __restrict__ dst,
                                                 int* __restrict__ cursor, int* __restrict__ esrc) {
    int e = blockIdx.x * 256 + threadIdx.x;
    if (e < NE) {
        int pos = atomicAdd(&cursor[dst[e]], 1);
        esrc[pos] = src[e];
    }
}

// ---------------- MFMA dual GEMM + fused att coefficients (+ in-block edge count on layer 1) ----------------
// 128 rows/block, 8 waves; wave w: rows w*16..+15 x 128 cols. W+Wskip (64 KB, pre-swizzled)
// staged to LDS once per block. Layer 1: each block also fires NE/GGEMM count atomics
// up front (no return value -> no waitcnt; overlaps the MFMA phase).

#define GGEMM ((NN + 127) / 128)  // 391

template <bool F32IN>
__global__ void __launch_bounds__(512) gemm2_k(const void* __restrict__ xin,
                                               const unsigned short* __restrict__ Wl,  // W | Wskip contiguous
                                               const float* __restrict__ a_src, const float* __restrict__ a_dst,
                                               unsigned short* __restrict__ h2, unsigned short* __restrict__ skipb,
                                               float* __restrict__ nsrc, float* __restrict__ ndst,
                                               const int* __restrict__ e_dst, int* __restrict__ counts) {
    __shared__ __align__(16) unsigned char wlds[65536];
    int tid = threadIdx.x;

    // fire-and-forget edge counting (layer 1 only), overlaps with everything below
    if (F32IN) {
        const int EPB = (NE + GGEMM - 1) / GGEMM;  // 1535
        int e0 = blockIdx.x * EPB;
        int e1 = e0 + EPB < NE ? e0 + EPB : NE;
        for (int ee = e0 + tid; ee < e1; ee += 512)
            atomicAdd(&counts[e_dst[ee]], 1);
    }

    int row0 = blockIdx.x * 128;
    int w = tid >> 6, lidx = tid & 63;
    int lrow = lidx & 15, lk = lidx >> 4;
    int srow = row0 + w * 16 + lrow;
    int rclamp = srow < NN ? srow : NN - 1;

    // A-fragment prefetch (4 kc x 16B)
    short8 afrag[4];
    if (F32IN) {
        const float* xp = (const float*)xin + (size_t)rclamp * DD;
#pragma unroll
        for (int kc = 0; kc < 4; ++kc) {
            float4 u0 = *(const float4*)(xp + kc * 32 + lk * 8);
            float4 u1 = *(const float4*)(xp + kc * 32 + lk * 8 + 4);
            short8 a;
            a[0] = (short)f2bf(u0.x); a[1] = (short)f2bf(u0.y);
            a[2] = (short)f2bf(u0.z); a[3] = (short)f2bf(u0.w);
            a[4] = (short)f2bf(u1.x); a[5] = (short)f2bf(u1.y);
            a[6] = (short)f2bf(u1.z); a[7] = (short)f2bf(u1.w);
            afrag[kc] = a;
        }
    } else {
        const unsigned short* xp = (const unsigned short*)xin + (size_t)rclamp * DD;
#pragma unroll
        for (int kc = 0; kc < 4; ++kc)
            afrag[kc] = *(const short8*)(xp + kc * 32 + lk * 8);
    }

    // stage 64 KB W|Wskip, linear copy (global layout is pre-swizzled)
    {
        const uint4* g = (const uint4*)Wl;
        uint4* l = (uint4*)wlds;
#pragma unroll
        for (int i = 0; i < 8; ++i)
            l[i * 512 + tid] = g[i * 512 + tid];
    }
    __syncthreads();

    f32x4 zero = {0.f, 0.f, 0.f, 0.f};
    f32x4 acch[8], accs[8];
#pragma unroll
    for (int t = 0; t < 8; ++t) { acch[t] = zero; accs[t] = zero; }

#pragma unroll
    for (int kc = 0; kc < 4; ++kc) {
        short8 a = afrag[kc];
#pragma unroll
        for (int t = 0; t < 8; ++t) {
            int off = (t * 16 + lrow) * 256 + (((kc * 4 + lk) ^ (lrow & 7)) * 16);
            short8 b  = *(const short8*)&wlds[off];
            short8 bs = *(const short8*)&wlds[off + 32768];
            acch[t] = __builtin_amdgcn_mfma_f32_16x16x32_bf16(a, b, acch[t], 0, 0, 0);
            accs[t] = __builtin_amdgcn_mfma_f32_16x16x32_bf16(a, bs, accs[t], 0, 0, 0);
        }
    }

    // D: col = lane&15, row = (lane>>4)*4 + reg
#pragma unroll
    for (int t = 0; t < 8; ++t) {
#pragma unroll
        for (int q = 0; q < 4; ++q) {
            int grow = row0 + w * 16 + lk * 4 + q;
            if (grow < NN) {
                int col = t * 16 + lrow;
                h2[(size_t)grow * DD + col] = f2bf(acch[t][q]);
                skipb[(size_t)grow * DD + col] = f2bf(accs[t][q]);
            }
        }
    }

    // fused att: nsrc[row][h] = sum_c h[row][32h+c]*a_src[h][c]  (f32 accs, 16-lane reduce)
    float as_lo[NH], as_hi[NH], ad_lo[NH], ad_hi[NH];
#pragma unroll
    for (int h = 0; h < NH; ++h) {
        as_lo[h] = a_src[h * 32 + lrow];
        as_hi[h] = a_src[h * 32 + 16 + lrow];
        ad_lo[h] = a_dst[h * 32 + lrow];
        ad_hi[h] = a_dst[h * 32 + 16 + lrow];
    }
#pragma unroll
    for (int h = 0; h < NH; ++h) {
#pragma unroll
        for (int q = 0; q < 4; ++q) {
            float ps = acch[2 * h][q] * as_lo[h] + acch[2 * h + 1][q] * as_hi[h];
            float pd = acch[2 * h][q] * ad_lo[h] + acch[2 * h + 1][q] * ad_hi[h];
#pragma unroll
            for (int off = 1; off < 16; off <<= 1) {
                ps += __shfl_xor(ps, off);
                pd += __shfl_xor(pd, off);
            }
            if (lrow == 0) {
                int grow = row0 + w * 16 + lk * 4 + q;
                if (grow < NN) {
                    nsrc[grow * 4 + h] = ps;
                    ndst[grow * 4 + h] = pd;
                }
            }
        }
    }
}

// ---------------- aggregate: single-pass online segment softmax + weighted bf16 gather ----------------
// 4 nodes/block (1 wave each). Lane i: weight for (edge-slot i&15, head i>>4);
// owns output channels 2i, 2i+1. 16 edges per chunk; tail slots skipped via
// wave-uniform cnt with statically unrolled predicated loads (keeps MLP + registers).

__global__ void __launch_bounds__(256) aggregate_k(const unsigned short* __restrict__ h2,
                                                   const unsigned short* __restrict__ skipb,
                                                   const float* __restrict__ nsrc, const float* __restrict__ ndst,
                                                   const int* __restrict__ offsets, const int* __restrict__ esrc,
                                                   const float* __restrict__ bias, float* __restrict__ outf,
                                                   unsigned short* __restrict__ outb) {
    int n = blockIdx.x * 4 + (threadIdx.x >> 6);
    int i = threadIdx.x & 63;
    int e = i & 15, hc = i >> 4;
    int gbase = i & 48;
    int beg = offsets[n], end = offsets[n + 1];
    float4 ndv = *(const float4*)&ndst[n * 4];
    float ad = sel4(ndv, hc);
    const unsigned int* h2w = (const unsigned int*)h2;

    float m = -1e30f, den = 0.f, acc0 = 0.f, acc1 = 0.f;
    for (int base = beg; base < end; base += 16) {
        int j = base + e;
        int jc = j < end ? j : end - 1;
        int s = esrc[jc];
        float4 nv = *(const float4*)&nsrc[s * 4];
        float a = sel4(nv, hc) + ad;
        a = a > 0.f ? a : NEG_SLOPE * a;
        if (j >= end) a = -1e30f;
        float cm = a;
        cm = fmaxf(cm, __shfl_xor(cm, 1));
        cm = fmaxf(cm, __shfl_xor(cm, 2));
        cm = fmaxf(cm, __shfl_xor(cm, 4));
        cm = fmaxf(cm, __shfl_xor(cm, 8));
        float mn = fmaxf(m, cm);
        float scale = __expf(m - mn);
        float wgt = __expf(a - mn);
        m = mn;
        float sw = wgt;
        sw += __shfl_xor(sw, 1);
        sw += __shfl_xor(sw, 2);
        sw += __shfl_xor(sw, 4);
        sw += __shfl_xor(sw, 8);
        den = den * scale + sw;
        acc0 *= scale;
        acc1 *= scale;

        int cnt = end - base; cnt = cnt < 16 ? cnt : 16;  // wave-uniform
        int sse[16]; float wwe[16]; unsigned hv[16];
#pragma unroll
        for (int e2 = 0; e2 < 16; ++e2) {
            sse[e2] = __shfl(s, e2);
            wwe[e2] = __shfl(wgt, gbase + e2);
        }
#pragma unroll
        for (int e2 = 0; e2 < 16; ++e2)
            if (e2 < cnt) hv[e2] = h2w[sse[e2] * 64 + i];
#pragma unroll
        for (int e2 = 0; e2 < 16; ++e2)
            if (e2 < cnt) {
                acc0 = fmaf(wwe[e2], bf2f((unsigned short)(hv[e2] & 0xFFFF)), acc0);
                acc1 = fmaf(wwe[e2], bf2f((unsigned short)(hv[e2] >> 16)), acc1);
            }
    }
    float inv = 1.f / (den + 1e-16f);
    int c0 = 2 * i;
    unsigned sk = ((const unsigned int*)skipb)[n * 64 + i];
    float2 bv = *(const float2*)&bias[c0];
    float o0 = acc0 * inv + bv.x + bf2f((unsigned short)(sk & 0xFFFF));
    float o1 = acc1 * inv + bv.y + bf2f((unsigned short)(sk >> 16));
    o0 = o0 > 0.f ? o0 : expm1f(o0);
    o1 = o1 > 0.f ? o1 : expm1f(o1);
    size_t o = (size_t)n * DD;
    if (outf) { outf[o + c0] = o0; outf[o + c0 + 1] = o1; }
    if (outb) { outb[o + c0] = f2bf(o0); outb[o + c0 + 1] = f2bf(o1); }
}

// ---------------- launch ----------------

extern "C" void kernel_launch(void* const* d_in, const int* in_sizes, int n_in,
                              void* d_out, int out_size, void* d_ws, size_t ws_size,
                              hipStream_t stream) {
    const float* x   = (const float*)d_in[0];
    const int* eidx  = (const int*)d_in[1];
    const float* W1  = (const float*)d_in[2];
    const float* as1 = (const float*)d_in[3];
    const float* ad1 = (const float*)d_in[4];
    const float* b1  = (const float*)d_in[5];
    const float* Ws1 = (const float*)d_in[6];
    const float* W2  = (const float*)d_in[7];
    const float* as2 = (const float*)d_in[8];
    const float* ad2 = (const float*)d_in[9];
    const float* b2  = (const float*)d_in[10];
    const float* Ws2 = (const float*)d_in[11];
    float* out = (float*)d_out;

    const int* e_src = eidx;
    const int* e_dst = eidx + NE;

    char* p = (char*)d_ws;
    unsigned short* h2    = (unsigned short*)p; p += (size_t)NN * DD * 2;
    unsigned short* xb    = (unsigned short*)p; p += (size_t)NN * DD * 2;
    unsigned short* skipb = (unsigned short*)p; p += (size_t)NN * DD * 2;
    float* nsrc = (float*)p; p += (size_t)NN * NH * 4;
    float* ndst = (float*)p; p += (size_t)NN * NH * 4;
    unsigned short* Wt = (unsigned short*)p; p += (size_t)4 * DD * DD * 2;
    int* counts  = (int*)p; p += (size_t)NN * 4;
    int* offsets = (int*)p; p += (size_t)(NN + 4) * 4;
    int* cursor  = (int*)p; p += (size_t)NN * 4;
    int* bsum    = (int*)p; p += 256 * 4;
    int* esrc    = (int*)p; p += (size_t)ET * 4;

    // prep (W transpose + counts=0)
    prep_k<<<256, 256, 0, stream>>>(W1, Ws1, W2, Ws2, Wt, counts);

    // layer 1 GEMM with in-block fire-and-forget edge counting
    gemm2_k<true><<<GGEMM, 512, 0, stream>>>(x, Wt, as1, ad1, h2, skipb, nsrc, ndst, e_dst, counts);

    // CSR finalize (two-level scan, coalesced + monotone)
    partial_k<<<NB, 256, 0, stream>>>(counts, bsum);
    offsets_k<<<NB, 256, 0, stream>>>(counts, bsum, offsets, cursor, esrc);
    scatter_k<<<(NE + 255) / 256, 256, 0, stream>>>(e_src, e_dst, cursor, esrc);

    // layer 1 aggregate
    aggregate_k<<<NN / 4, 256, 0, stream>>>(h2, skipb, nsrc, ndst, offsets, esrc, b1, nullptr, xb);

    // layer 2
    gemm2_k<false><<<GGEMM, 512, 0, stream>>>(xb, Wt + 32768, as2, ad2, h2, skipb, nsrc, ndst, e_dst, counts);
    aggregate_k<<<NN / 4, 256, 0, stream>>>(h2, skipb, nsrc, ndst, offsets, esrc, b2, out, nullptr);
}

// Round 11
// 248.336 us; speedup vs baseline: 1.1976x; 1.1976x over previous
//
#include <hip/hip_runtime.h>
#include <hip/hip_bf16.h>

#define NN 50000
#define NE 600000
#define DD 128
#define NH 4
#define ET (NE + NN)
#define NEG_SLOPE 0.2f
#define NB 196  // ceil(NN/256) scan blocks

typedef __attribute__((ext_vector_type(8))) short short8;
typedef __attribute__((ext_vector_type(4))) float f32x4;

__device__ __forceinline__ float bf2f(unsigned short u) {
    union { unsigned int i; float f; } c; c.i = ((unsigned int)u) << 16; return c.f;
}
__device__ __forceinline__ unsigned short f2bf(float f) {
    union { float f; unsigned int i; } c; c.f = f;
    unsigned int r = c.i + 0x7FFF + ((c.i >> 16) & 1);  // RNE
    return (unsigned short)(r >> 16);
}

// ---------------- prep: W->bf16, transposed [col][k], chunk-swizzled; counts=0 ----------------
// Layout: Wt[mat*16384 + col*128 + cs*8 + j] = W[k][col], where c = cs^(col&7), k = c*8+j.

__global__ void __launch_bounds__(256) prep_k(const float* __restrict__ W1, const float* __restrict__ Ws1,
                                              const float* __restrict__ W2, const float* __restrict__ Ws2,
                                              unsigned short* __restrict__ Wt, int* __restrict__ counts) {
    int idx = blockIdx.x * 256 + threadIdx.x;  // 0..65535
    int mat = idx >> 14;
    int p = idx & 16383;
    int col = p >> 7;
    int cs = (p >> 3) & 15;
    int j = p & 7;
    int c = cs ^ (col & 7);
    int k = c * 8 + j;
    const float* Wsrc = (mat == 0) ? W1 : (mat == 1) ? Ws1 : (mat == 2) ? W2 : Ws2;
    Wt[idx] = f2bf(Wsrc[k * DD + col]);
    if (idx < NN) counts[idx] = 0;  // real-edge count only; +1 self loop added in scan
}

// ---------------- two-level scan, 2 dispatches (coalesced + monotone) ----------------

__global__ void __launch_bounds__(256) partial_k(const int* __restrict__ counts, int* __restrict__ bsum) {
    __shared__ int tmp[256];
    int t = blockIdx.x * 256 + threadIdx.x;
    int v = (t < NN) ? counts[t] + 1 : 0;  // +1 self loop
    tmp[threadIdx.x] = v;
    __syncthreads();
    for (int off = 128; off > 0; off >>= 1) {
        if (threadIdx.x < off) tmp[threadIdx.x] += tmp[threadIdx.x + off];
        __syncthreads();
    }
    if (threadIdx.x == 0) bsum[blockIdx.x] = tmp[0];
}

// each block recomputes the global prefix of block sums itself (196 ints), then local scan
__global__ void __launch_bounds__(256) offsets_k(const int* __restrict__ counts, const int* __restrict__ bsum,
                                                 int* __restrict__ offsets, int* __restrict__ cursor,
                                                 int* __restrict__ esrc) {
    __shared__ int bs[256];
    __shared__ int tmp[256];
    int b = blockIdx.x, tid = threadIdx.x;
    int bv = (tid < NB) ? bsum[tid] : 0;
    bs[tid] = bv;
    __syncthreads();
    for (int off = 1; off < 256; off <<= 1) {
        int u = (tid >= off) ? bs[tid - off] : 0;
        __syncthreads();
        bs[tid] += u;
        __syncthreads();
    }
    int boff = (b == 0) ? 0 : bs[b - 1];

    int t = b * 256 + tid;
    int c = (t < NN) ? counts[t] : 0;
    int v = (t < NN) ? c + 1 : 0;
    tmp[tid] = v;
    __syncthreads();
    for (int off = 1; off < 256; off <<= 1) {
        int u = (tid >= off) ? tmp[tid - off] : 0;
        __syncthreads();
        tmp[tid] += u;
        __syncthreads();
    }
    if (t < NN) {
        int o = boff + tmp[tid] - v;
        offsets[t] = o;
        cursor[t] = o;
        esrc[o + c] = t;  // self loop in the last slot of the segment
    }
    if (b == 0 && tid == 0) offsets[NN] = ET;
}

__global__ void __launch_bounds__(256) scatter_k(const int* __restrict__ src, const int* __restrict__ dst,
                                                 int* __restrict__ cursor, int* __restrict__ esrc) {
    int e = blockIdx.x * 256 + threadIdx.x;
    if (e < NE) {
        int pos = atomicAdd(&cursor[dst[e]], 1);
        esrc[pos] = src[e];
    }
}

// ---------------- MFMA dual GEMM + fused att coefficients (+ fused edge count on layer 1) ----------------
// 128 rows/block, 8 waves; wave w: rows w*16..+15 x 128 cols. W+Wskip (64 KB, pre-swizzled)
// staged to LDS once per block. Blocks >= GGEMM (layer 1 only) do the CSR edge counting.

#define GGEMM ((NN + 127) / 128)  // 391

template <bool F32IN>
__global__ void __launch_bounds__(512) gemm2_k(const void* __restrict__ xin,
                                               const unsigned short* __restrict__ Wl,  // W | Wskip contiguous
                                               const float* __restrict__ a_src, const float* __restrict__ a_dst,
                                               unsigned short* __restrict__ h2, unsigned short* __restrict__ skipb,
                                               float* __restrict__ nsrc, float* __restrict__ ndst,
                                               const int* __restrict__ e_dst, int* __restrict__ counts) {
    __shared__ __align__(16) unsigned char wlds[65536];
    if (F32IN && blockIdx.x >= GGEMM) {  // fused edge-count blocks (layer 1 launch only)
        int e = (blockIdx.x - GGEMM) * 512 + threadIdx.x;
        if (e < NE) atomicAdd(&counts[e_dst[e]], 1);
        return;
    }
    int row0 = blockIdx.x * 128;
    int tid = threadIdx.x;
    int w = tid >> 6, lidx = tid & 63;
    int lrow = lidx & 15, lk = lidx >> 4;
    int srow = row0 + w * 16 + lrow;
    int rclamp = srow < NN ? srow : NN - 1;

    // A-fragment prefetch (4 kc x 16B)
    short8 afrag[4];
    if (F32IN) {
        const float* xp = (const float*)xin + (size_t)rclamp * DD;
#pragma unroll
        for (int kc = 0; kc < 4; ++kc) {
            float4 u0 = *(const float4*)(xp + kc * 32 + lk * 8);
            float4 u1 = *(const float4*)(xp + kc * 32 + lk * 8 + 4);
            short8 a;
            a[0] = (short)f2bf(u0.x); a[1] = (short)f2bf(u0.y);
            a[2] = (short)f2bf(u0.z); a[3] = (short)f2bf(u0.w);
            a[4] = (short)f2bf(u1.x); a[5] = (short)f2bf(u1.y);
            a[6] = (short)f2bf(u1.z); a[7] = (short)f2bf(u1.w);
            afrag[kc] = a;
        }
    } else {
        const unsigned short* xp = (const unsigned short*)xin + (size_t)rclamp * DD;
#pragma unroll
        for (int kc = 0; kc < 4; ++kc)
            afrag[kc] = *(const short8*)(xp + kc * 32 + lk * 8);
    }

    // stage 64 KB W|Wskip, linear copy (global layout is pre-swizzled)
    {
        const uint4* g = (const uint4*)Wl;
        uint4* l = (uint4*)wlds;
#pragma unroll
        for (int i = 0; i < 8; ++i)
            l[i * 512 + tid] = g[i * 512 + tid];
    }
    __syncthreads();

    f32x4 zero = {0.f, 0.f, 0.f, 0.f};
    f32x4 acch[8], accs[8];
#pragma unroll
    for (int t = 0; t < 8; ++t) { acch[t] = zero; accs[t] = zero; }

#pragma unroll
    for (int kc = 0; kc < 4; ++kc) {
        short8 a = afrag[kc];
#pragma unroll
        for (int t = 0; t < 8; ++t) {
            int off = (t * 16 + lrow) * 256 + (((kc * 4 + lk) ^ (lrow & 7)) * 16);
            short8 b  = *(const short8*)&wlds[off];
            short8 bs = *(const short8*)&wlds[off + 32768];
            acch[t] = __builtin_amdgcn_mfma_f32_16x16x32_bf16(a, b, acch[t], 0, 0, 0);
            accs[t] = __builtin_amdgcn_mfma_f32_16x16x32_bf16(a, bs, accs[t], 0, 0, 0);
        }
    }

    // D: col = lane&15, row = (lane>>4)*4 + reg
#pragma unroll
    for (int t = 0; t < 8; ++t) {
#pragma unroll
        for (int q = 0; q < 4; ++q) {
            int grow = row0 + w * 16 + lk * 4 + q;
            if (grow < NN) {
                int col = t * 16 + lrow;
                h2[(size_t)grow * DD + col] = f2bf(acch[t][q]);
                skipb[(size_t)grow * DD + col] = f2bf(accs[t][q]);
            }
        }
    }

    // fused att: nsrc[row][h] = sum_c h[row][32h+c]*a_src[h][c]  (f32 accs, 16-lane reduce)
    float as_lo[NH], as_hi[NH], ad_lo[NH], ad_hi[NH];
#pragma unroll
    for (int h = 0; h < NH; ++h) {
        as_lo[h] = a_src[h * 32 + lrow];
        as_hi[h] = a_src[h * 32 + 16 + lrow];
        ad_lo[h] = a_dst[h * 32 + lrow];
        ad_hi[h] = a_dst[h * 32 + 16 + lrow];
    }
#pragma unroll
    for (int h = 0; h < NH; ++h) {
#pragma unroll
        for (int q = 0; q < 4; ++q) {
            float ps = acch[2 * h][q] * as_lo[h] + acch[2 * h + 1][q] * as_hi[h];
            float pd = acch[2 * h][q] * ad_lo[h] + acch[2 * h + 1][q] * ad_hi[h];
#pragma unroll
            for (int off = 1; off < 16; off <<= 1) {
                ps += __shfl_xor(ps, off);
                pd += __shfl_xor(pd, off);
            }
            if (lrow == 0) {
                int grow = row0 + w * 16 + lk * 4 + q;
                if (grow < NN) {
                    nsrc[grow * 4 + h] = ps;
                    ndst[grow * 4 + h] = pd;
                }
            }
        }
    }
}

// ---------------- aggregate: single-pass online segment softmax + weighted bf16 gather ----------------
// 4 nodes/block (1 wave each). Lane i: weight for (edge-slot i&15, head i>>4);
// owns output channels 2i, 2i+1. 16 edges per chunk.

__global__ void __launch_bounds__(256) aggregate_k(const unsigned short* __restrict__ h2,
                                                   const unsigned short* __restrict__ skipb,
                                                   const float* __restrict__ nsrc, const float* __restrict__ ndst,
                                                   const int* __restrict__ offsets, const int* __restrict__ esrc,
                                                   const float* __restrict__ bias, float* __restrict__ outf,
                                                   unsigned short* __restrict__ outb) {
    int n = blockIdx.x * 4 + (threadIdx.x >> 6);
    int i = threadIdx.x & 63;
    int e = i & 15, hc = i >> 4;
    int gbase = i & 48;
    int beg = offsets[n], end = offsets[n + 1];
    float ad = ndst[n * 4 + hc];
    const unsigned int* h2w = (const unsigned int*)h2;

    float m = -1e30f, den = 0.f, acc0 = 0.f, acc1 = 0.f;
    for (int base = beg; base < end; base += 16) {
        int j = base + e;
        int jc = j < end ? j : end - 1;
        int s = esrc[jc];
        float a = nsrc[s * 4 + hc] + ad;
        a = a > 0.f ? a : NEG_SLOPE * a;
        if (j >= end) a = -1e30f;
        float cm = a;
        cm = fmaxf(cm, __shfl_xor(cm, 1));
        cm = fmaxf(cm, __shfl_xor(cm, 2));
        cm = fmaxf(cm, __shfl_xor(cm, 4));
        cm = fmaxf(cm, __shfl_xor(cm, 8));
        float mn = fmaxf(m, cm);
        float scale = __expf(m - mn);
        float wgt = __expf(a - mn);
        m = mn;
        float sw = wgt;
        sw += __shfl_xor(sw, 1);
        sw += __shfl_xor(sw, 2);
        sw += __shfl_xor(sw, 4);
        sw += __shfl_xor(sw, 8);
        den = den * scale + sw;
        acc0 *= scale;
        acc1 *= scale;
#pragma unroll
        for (int e2 = 0; e2 < 16; ++e2) {
            int se = __shfl(s, e2);
            float we = __shfl(wgt, gbase + e2);
            unsigned hv = h2w[se * 64 + i];
            acc0 = fmaf(we, bf2f((unsigned short)(hv & 0xFFFF)), acc0);
            acc1 = fmaf(we, bf2f((unsigned short)(hv >> 16)), acc1);
        }
    }
    float inv = 1.f / (den + 1e-16f);
    int c0 = 2 * i;
    unsigned sk = ((const unsigned int*)skipb)[n * 64 + i];
    float2 bv = *(const float2*)&bias[c0];
    float o0 = acc0 * inv + bv.x + bf2f((unsigned short)(sk & 0xFFFF));
    float o1 = acc1 * inv + bv.y + bf2f((unsigned short)(sk >> 16));
    o0 = o0 > 0.f ? o0 : expm1f(o0);
    o1 = o1 > 0.f ? o1 : expm1f(o1);
    size_t o = (size_t)n * DD;
    if (outf) { outf[o + c0] = o0; outf[o + c0 + 1] = o1; }
    if (outb) { outb[o + c0] = f2bf(o0); outb[o + c0 + 1] = f2bf(o1); }
}

// ---------------- launch ----------------

extern "C" void kernel_launch(void* const* d_in, const int* in_sizes, int n_in,
                              void* d_out, int out_size, void* d_ws, size_t ws_size,
                              hipStream_t stream) {
    const float* x   = (const float*)d_in[0];
    const int* eidx  = (const int*)d_in[1];
    const float* W1  = (const float*)d_in[2];
    const float* as1 = (const float*)d_in[3];
    const float* ad1 = (const float*)d_in[4];
    const float* b1  = (const float*)d_in[5];
    const float* Ws1 = (const float*)d_in[6];
    const float* W2  = (const float*)d_in[7];
    const float* as2 = (const float*)d_in[8];
    const float* ad2 = (const float*)d_in[9];
    const float* b2  = (const float*)d_in[10];
    const float* Ws2 = (const float*)d_in[11];
    float* out = (float*)d_out;

    const int* e_src = eidx;
    const int* e_dst = eidx + NE;

    char* p = (char*)d_ws;
    unsigned short* h2    = (unsigned short*)p; p += (size_t)NN * DD * 2;
    unsigned short* xb    = (unsigned short*)p; p += (size_t)NN * DD * 2;
    unsigned short* skipb = (unsigned short*)p; p += (size_t)NN * DD * 2;
    float* nsrc = (float*)p; p += (size_t)NN * NH * 4;
    float* ndst = (float*)p; p += (size_t)NN * NH * 4;
    unsigned short* Wt = (unsigned short*)p; p += (size_t)4 * DD * DD * 2;
    int* counts  = (int*)p; p += (size_t)NN * 4;
    int* offsets = (int*)p; p += (size_t)(NN + 4) * 4;
    int* cursor  = (int*)p; p += (size_t)NN * 4;
    int* bsum    = (int*)p; p += 256 * 4;
    int* esrc    = (int*)p; p += (size_t)ET * 4;

    const int CB = (NE + 511) / 512;  // 1172 count blocks fused into gemm1

    // prep (W transpose + counts=0)
    prep_k<<<256, 256, 0, stream>>>(W1, Ws1, W2, Ws2, Wt, counts);

    // layer 1 GEMM + fused edge counting
    gemm2_k<true><<<GGEMM + CB, 512, 0, stream>>>(x, Wt, as1, ad1, h2, skipb, nsrc, ndst, e_dst, counts);

    // CSR finalize (two-level scan, coalesced + monotone)
    partial_k<<<NB, 256, 0, stream>>>(counts, bsum);
    offsets_k<<<NB, 256, 0, stream>>>(counts, bsum, offsets, cursor, esrc);
    scatter_k<<<(NE + 255) / 256, 256, 0, stream>>>(e_src, e_dst, cursor, esrc);

    // layer 1 aggregate
    aggregate_k<<<NN / 4, 256, 0, stream>>>(h2, skipb, nsrc, ndst, offsets, esrc, b1, nullptr, xb);

    // layer 2
    gemm2_k<false><<<GGEMM, 512, 0, stream>>>(xb, Wt + 32768, as2, ad2, h2, skipb, nsrc, ndst, e_dst, counts);
    aggregate_k<<<NN / 4, 256, 0, stream>>>(h2, skipb, nsrc, ndst, offsets, esrc, b2, out, nullptr);
}